// Round 1
// baseline (20349.353 us; speedup 1.0000x reference)
//
#include <hip/hip_runtime.h>

// mRNN: h_{t+1} = h + 0.1*(-h + relu(h) @ W_eff^T + tonic + ext) + 0.01*noise
// out[b,t] = sum_alm relu(h[500:600]) * out_w
//
// Strategy: 1 WG per batch (128 WGs, 512 thr = 8 waves). W_eff is block-sparse
// (11 region blocks, ~97k nz). Prep kernel packs it as f16 pairs, quad-padded,
// [block][half][q][lane] (lane = target row). Main kernel loads ALL W into
// per-lane REGISTERS once (max 36 uint4 = 144 VGPR/lane), then iterates 1000
// steps: r=relu(h) kept in double-buffered f16 LDS; r quads read as uniform
// ds_read_b128 broadcasts; MACs via fma_mix-friendly (float)f16*(float)f16.

typedef _Float16 f16;
typedef _Float16 h2v __attribute__((ext_vector_type(2)));

__device__ __forceinline__ unsigned pack_f16x2(float a, float b){
  union { f16 h[2]; unsigned u; } cv;
  cv.h[0] = (f16)a; cv.h[1] = (f16)b;
  return cv.u;
}

// 2 MACs: acc += w.lo*r.lo + w.hi*r.hi  (f16 inputs, f32 accumulate)
__device__ __forceinline__ void mac2(unsigned w, unsigned r, float& acc){
  union { unsigned u; h2v v; } cw, cr;
  cw.u = w; cr.u = r;
  acc += (float)cw.v.x * (float)cr.v.x;
  acc += (float)cw.v.y * (float)cr.v.y;
}

// ---------------- block tables ----------------
// 11 blocks: (qoff in uint4 units, Q quads/row, tgt_base, src extent, r-pair base)
// quad = 4 f16 pairs = 8 sources, aligned so r reads are 16B-aligned.
namespace tb {
constexpr int qoffs[12] = {0,1300,2600,3600,4900,5600,6900,7600,8900,10200,11500,12800};
constexpr int Qs [11] = {13,13,10,13, 7,13, 7,13,13,13,13};
constexpr int tgt[11] = {0,0,0,0,100,200,300,300,400,500,500};
constexpr int slo[11] = {0,400,500,600, 50,100,  0,200,300,400,500};
constexpr int shi[11] = {100,500,570,700,100,200, 50,300,400,500,600};
constexpr int rpb[11] = {0,200,248,300, 24, 48,  0,100,148,200,248};
}

// ---------------- prep: pack W_eff ----------------
__device__ __forceinline__ float wval(const float* __restrict__ Wrec,
    const float* __restrict__ Wm, const float* __restrict__ Ws,
    const float* __restrict__ Wf, int i, int j, int lo, int hi){
  if (j < lo || j >= hi) return 0.f;
  int idx = i*700 + j;
  return fmaxf(Wrec[idx], 0.f)*Wm[idx]*Ws[idx] + Wf[idx];
}

__global__ void prep_kernel(const float* __restrict__ Wrec, const float* __restrict__ Wm,
                            const float* __restrict__ Ws, const float* __restrict__ Wf,
                            uint4* __restrict__ Wp){
  int s = blockIdx.x*blockDim.x + threadIdx.x;
  if (s >= 12800) return;
  int blk = 0;
  while (s >= tb::qoffs[blk+1]) ++blk;
  int rel = s - tb::qoffs[blk];
  int Q = tb::Qs[blk];
  int half, q, lane;
  if (rel < Q*64){ half = 0; q = rel >> 6; lane = rel & 63; }
  else { int r2 = rel - Q*64; half = 1; q = r2/36; lane = r2 - q*36; }
  int i = tb::tgt[blk] + half*64 + lane;
  unsigned pk[4];
  #pragma unroll
  for (int p = 0; p < 4; ++p){
    int pr = tb::rpb[blk] + q*4 + p;
    float v0 = wval(Wrec,Wm,Ws,Wf, i, 2*pr,   tb::slo[blk], tb::shi[blk]);
    float v1 = wval(Wrec,Wm,Ws,Wf, i, 2*pr+1, tb::slo[blk], tb::shi[blk]);
    pk[p] = pack_f16x2(v0, v1);
  }
  Wp[s] = make_uint4(pk[0], pk[1], pk[2], pk[3]);
}

// ---------------- per-wave config ----------------
namespace cfg {
constexpr int  NL [8] = {64,64,36,36,64,36,64,36};
constexpr int  Q0 [8] = {13,10,13,10,13,13, 7, 7};
constexpr int  Q1 [8] = {13,13,13,13,13,13,13,13};
constexpr int  Q2 [8] = { 7,13, 7,13, 0, 0,13,13};
constexpr int  QO0[8] = {0,2600,832,3240,10200,11032,6900,7348};
constexpr int  QO1[8] = {1300,3600,2132,4432,11500,12332,7600,8432};
constexpr int  QO2[8] = {4900,5600,5348,6432,0,0,8900,9732};
constexpr int  RP0[8] = {0,248,0,248,200,200,0,0};
constexpr int  RP1[8] = {200,300,200,300,248,248,100,100};
constexpr int  RP2[8] = {24,48,24,48,0,0,148,148};
constexpr int  AS0[8] = {0,2,0,2,0,0,0,0};   // 0->acc0, 1->acc1, 2->partial
constexpr int  AS1[8] = {0,2,0,2,0,0,0,0};
constexpr int  AS2[8] = {1,1,1,1,0,0,1,1};
constexpr int  I0 [8] = {0,-1,64,-1,500,564,300,364};  // owned target 0 base (-1: none)
constexpr int  I1 [8] = {100,200,164,264,600,664,400,464}; // owned target 1 base
constexpr bool ITI[8] = {false,false,false,false,true,true,false,false};
constexpr bool PW [8] = {false,true,false,true,false,false,false,false}; // writes str partial
constexpr bool PR [8] = {true,false,true,false,false,false,false,false}; // reads str partial
constexpr int  PB [8] = {0,0,64,64,0,0,0,0};
constexpr bool OUT[8] = {false,false,false,false,true,true,false,false};
constexpr int  OWB[8] = {0,0,0,0,0,64,0,0};
}

template<int Q>
__device__ __forceinline__ float dot_block(const uint4 (&w)[Q],
    const f16* __restrict__ rc, int rpb){
  // 4 independent accumulation chains to hide FMA latency
  float ax = 0.f, ay = 0.f, az = 0.f, aw = 0.f;
  const uint4* rq = (const uint4*)(rc + 2*rpb);
  #pragma unroll
  for (int q = 0; q < Q; ++q){
    uint4 r = rq[q];                 // uniform-address LDS broadcast (b128)
    mac2(w[q].x, r.x, ax);
    mac2(w[q].y, r.y, ay);
    mac2(w[q].z, r.z, az);
    mac2(w[q].w, r.w, aw);
  }
  return (ax + ay) + (az + aw);
}

template<int WID>
__device__ __forceinline__ void wave_loop(const float* __restrict__ inp,
    const float* __restrict__ noise, const float* __restrict__ tonic,
    const float* __restrict__ outw, const uint4* __restrict__ Wp,
    float* __restrict__ out, int b, int lane,
    f16 (*rbuf)[704], float* part_str, float* out_part){
  using namespace cfg;
  constexpr int nl = NL[WID];
  constexpr int q0 = Q0[WID], q1 = Q1[WID], q2 = Q2[WID];
  const bool act = lane < nl;

  // --- load this wave's W slices into registers (once) ---
  uint4 w0[q0], w1[q1], w2[(q2 > 0) ? q2 : 1];
  if (act){
    #pragma unroll
    for (int q = 0; q < q0; ++q) w0[q] = Wp[QO0[WID] + q*nl + lane];
    #pragma unroll
    for (int q = 0; q < q1; ++q) w1[q] = Wp[QO1[WID] + q*nl + lane];
    if constexpr (q2 > 0){
      #pragma unroll
      for (int q = 0; q < q2; ++q) w2[q] = Wp[QO2[WID] + q*nl + lane];
    }
  }
  float ton0 = 0.f, ton1 = 0.f, ow = 0.f;
  if (act){
    if constexpr (I0[WID] >= 0) ton0 = tonic[I0[WID] + lane];
    ton1 = tonic[I1[WID] + lane];
  }
  if constexpr (OUT[WID]) { if (act) ow = outw[OWB[WID] + lane]; }

  float h0 = 0.f, h1 = 0.f;
  for (int t = 0; t < 1000; ++t){
    const f16* rc = rbuf[t & 1];
    f16* rn = rbuf[(t + 1) & 1];
    // issue global loads early (hidden under the matvec)
    const size_t nb = ((size_t)b*1000 + t)*700;
    float n0 = 0.f, n1 = 0.f, x1 = 0.f;
    if (act){
      if constexpr (I0[WID] >= 0) n0 = noise[nb + I0[WID] + lane];
      n1 = noise[nb + I1[WID] + lane];
      if constexpr (ITI[WID])
        x1 = inp[((size_t)b*1000 + t)*100 + (I1[WID] - 600) + lane];
    }
    // ---- phase A: matvec from r_cur ----
    float a0 = 0.f, a1 = 0.f, aP = 0.f;
    if (act){
      { float r = dot_block<q0>(w0, rc, RP0[WID]);
        if constexpr (AS0[WID]==0) a0 += r; else if constexpr (AS0[WID]==1) a1 += r; else aP += r; }
      { float r = dot_block<q1>(w1, rc, RP1[WID]);
        if constexpr (AS1[WID]==0) a0 += r; else if constexpr (AS1[WID]==1) a1 += r; else aP += r; }
      if constexpr (q2 > 0){
        float r = dot_block<q2>(w2, rc, RP2[WID]);
        if constexpr (AS2[WID]==0) a0 += r; else if constexpr (AS2[WID]==1) a1 += r; else aP += r; }
    }
    if constexpr (PW[WID]) { if (act) part_str[PB[WID] + lane] = aP; }
    __syncthreads();   // barrier 1: partials visible; r_cur reads done
    // ---- phase B: h update, write r_next ----
    if (act){
      if constexpr (I0[WID] >= 0){
        float d0 = a0 + ton0;
        if constexpr (PR[WID]) d0 += part_str[PB[WID] + lane];
        h0 = h0 + 0.1f*(-h0 + d0) + 0.01f*n0;
        rn[I0[WID] + lane] = (f16)fmaxf(h0, 0.f);
      }
      {
        float ext = 0.f;
        if constexpr (ITI[WID]) ext = x1 + 0.01f*n1;
        float d1 = a1 + ton1 + ext;
        h1 = h1 + 0.1f*(-h1 + d1) + 0.01f*n1;
        rn[I1[WID] + lane] = (f16)fmaxf(h1, 0.f);
      }
    }
    if constexpr (OUT[WID]){
      float op = act ? fmaxf(h0, 0.f)*ow : 0.f;
      #pragma unroll
      for (int d = 32; d > 0; d >>= 1) op += __shfl_xor(op, d);
      if (lane == 0) out_part[WID - 4] = op;
    }
    __syncthreads();   // barrier 2: r_next + out partials visible
    if constexpr (WID == 0){
      if (lane == 0) out[(size_t)b*1000 + t] = out_part[0] + out_part[1];
    }
  }
}

__global__ __launch_bounds__(512, 2)
void rnn_kernel(const float* __restrict__ inp, const float* __restrict__ noise,
                const float* __restrict__ tonic, const float* __restrict__ outw,
                const uint4* __restrict__ Wp, float* __restrict__ out){
  __shared__ __align__(16) f16 rbuf[2][704];
  __shared__ float part_str[100];
  __shared__ float out_part[2];
  const int tid = threadIdx.x;
  for (int k = tid; k < 704; k += 512){ rbuf[0][k] = (f16)0.f; rbuf[1][k] = (f16)0.f; }
  __syncthreads();
  const int wid = tid >> 6, lane = tid & 63;
  const int b = blockIdx.x;
  switch (wid){
    case 0: wave_loop<0>(inp,noise,tonic,outw,Wp,out,b,lane,rbuf,part_str,out_part); break;
    case 1: wave_loop<1>(inp,noise,tonic,outw,Wp,out,b,lane,rbuf,part_str,out_part); break;
    case 2: wave_loop<2>(inp,noise,tonic,outw,Wp,out,b,lane,rbuf,part_str,out_part); break;
    case 3: wave_loop<3>(inp,noise,tonic,outw,Wp,out,b,lane,rbuf,part_str,out_part); break;
    case 4: wave_loop<4>(inp,noise,tonic,outw,Wp,out,b,lane,rbuf,part_str,out_part); break;
    case 5: wave_loop<5>(inp,noise,tonic,outw,Wp,out,b,lane,rbuf,part_str,out_part); break;
    case 6: wave_loop<6>(inp,noise,tonic,outw,Wp,out,b,lane,rbuf,part_str,out_part); break;
    default: wave_loop<7>(inp,noise,tonic,outw,Wp,out,b,lane,rbuf,part_str,out_part); break;
  }
}

extern "C" void kernel_launch(void* const* d_in, const int* in_sizes, int n_in,
                              void* d_out, int out_size, void* d_ws, size_t ws_size,
                              hipStream_t stream){
  const float* inp   = (const float*)d_in[0];
  const float* noise = (const float*)d_in[1];
  const float* Wrec  = (const float*)d_in[2];
  const float* Wmask = (const float*)d_in[3];
  const float* Wsign = (const float*)d_in[4];
  const float* Wfix  = (const float*)d_in[5];
  const float* tonic = (const float*)d_in[6];
  const float* outw  = (const float*)d_in[7];
  float* out = (float*)d_out;
  uint4* Wp = (uint4*)d_ws;    // 12800 * 16B = 204.8 KB packed weights

  prep_kernel<<<50, 256, 0, stream>>>(Wrec, Wmask, Wsign, Wfix, Wp);
  rnn_kernel<<<128, 512, 0, stream>>>(inp, noise, tonic, outw, Wp, out);
}